// Round 8
// baseline (184.613 us; speedup 1.0000x reference)
//
#include <hip/hip_runtime.h>
#include <hip/hip_bf16.h>
#include <float.h>

#define B_    16
#define N1_   4096
#define N2_   1024
#define C2_   256
#define OUT_  256
#define K_    4096    // GEMM K == N1
#define SPLITK 8
#define KCH_  (K_ / SPLITK)     // 512
#define ZSLAB 1048576           // floats per partial slab (16*256*256)

typedef short short8 __attribute__((ext_vector_type(8)));
typedef float float4v __attribute__((ext_vector_type(4)));

static __device__ __forceinline__ unsigned short f32_to_bf16_bits(float v) {
    __hip_bfloat16 h = __float2bfloat16(v);
    return *(unsigned short*)&h;
}

// ---------------------------------------------------------------------------
// Kernel 0a: convert W1 f32 -> bf16 for the MFMA GEMM.
// ---------------------------------------------------------------------------
__global__ __launch_bounds__(256) void w1cvt_kernel(
    const float* __restrict__ W1, unsigned short* __restrict__ W1b)
{
    const int i = (blockIdx.x * 256 + threadIdx.x) * 4;
    float4 v = *(const float4*)(W1 + i);
    ushort4 o;
    o.x = f32_to_bf16_bits(v.x);
    o.y = f32_to_bf16_bits(v.y);
    o.z = f32_to_bf16_bits(v.z);
    o.w = f32_to_bf16_bits(v.w);
    *(ushort4*)(W1b + i) = o;
}

// ---------------------------------------------------------------------------
// Kernel 0b: pts4[b][j] = (x, y, z, 0.5*|p|^2) for the knn scan.
// ---------------------------------------------------------------------------
__global__ __launch_bounds__(256) void ptsprep_kernel(
    const float* __restrict__ xyz2, float4* __restrict__ pts4)
{
    const int i = blockIdx.x * 256 + threadIdx.x;   // b*N2 + j, grid 64 blocks
    const float* p = xyz2 + (size_t)i * 3;
    float x = p[0], y = p[1], z = p[2];
    pts4[i] = make_float4(x, y, z, 0.5f * ((x * x + y * y) + z * z));
}

// ---------------------------------------------------------------------------
// Fused knn + interp. Key = DISTANCE dk = max(ss + 2*(0.5|p|^2 - dot), 0)
// (non-negative -> float order == bit order), with the global candidate
// index packed into the low 10 mantissa bits. Truncation is 2^-13 relative
// to d itself, so any selection flip is between neighbors whose weights
// match to ~1e-4 (benign). Smaller index wins ties (JAX stable top-k).
// Top-3 kept by a 4-op float network (min / med3 / min(max)). Candidates
// are wave-uniform -> scalar loads from pts4. Winners' distances are
// recomputed exactly for the weights. Phase B: gather x2 rows, blend,
// LDS-transpose, write bf16 interp_t[b][c][n] (K-major).
// ---------------------------------------------------------------------------
#define TPAD 65
union ShUnion {
    float pf[4][64][3];               // packed per-wave top-3   3 KB
    unsigned short tile[C2_][TPAD];   // transpose tile          33.3 KB
};

__global__ __launch_bounds__(256) void knn_interp_kernel(
    const float* __restrict__ xyz1,
    const float4* __restrict__ pts4,
    const float* __restrict__ x2,
    unsigned short* __restrict__ interp_t)
{
    __shared__ ShUnion sh;
    __shared__ float rw[64][3];
    __shared__ int   ri[64][3];

    const int b  = blockIdx.y;
    const int n0 = blockIdx.x * 64;
    const int t  = threadIdx.x;
    const int w  = t >> 6;
    const int l  = t & 63;

    const int n1 = n0 + l;
    const float* q = xyz1 + ((size_t)b * N1_ + n1) * 3;
    const float s0 = q[0], s1 = q[1], s2 = q[2];
    const float ss = (s0 * s0 + s1 * s1) + s2 * s2;

    // ---- Phase A: scan (wave-uniform candidates -> scalar loads) ----
    const int jbase = __builtin_amdgcn_readfirstlane(w << 8);   // 0,256,512,768
    const float4* pw = pts4 + (size_t)b * N2_ + jbase;

    float f0 = FLT_MAX, f1 = FLT_MAX, f2 = FLT_MAX;

    #pragma unroll 4
    for (int jj = 0; jj < 256; ++jj) {
        float4 pq = pw[jj];
        float dot = s0 * pq.x;
        dot = fmaf(s1, pq.y, dot);
        dot = fmaf(s2, pq.z, dot);
        // dk = ss + 2*(0.5|p|^2 - dot), clamped non-negative
        float dk = fmaxf(fmaf(2.0f, pq.w - dot, ss), 0.0f);
        float fp = __int_as_float((__float_as_int(dk) & 0xFFFFFC00) | (jbase + jj));
        float nf0 = fminf(fp, f0);
        float nf1 = __builtin_amdgcn_fmed3f(fp, f0, f1);
        float nf2 = fminf(f2, fmaxf(fp, f1));
        f0 = nf0; f1 = nf1; f2 = nf2;
    }

    sh.pf[w][l][0] = f0; sh.pf[w][l][1] = f1; sh.pf[w][l][2] = f2;
    __syncthreads();

    if (w == 0) {
        float g0 = FLT_MAX, g1 = FLT_MAX, g2 = FLT_MAX;
        #pragma unroll
        for (int p = 0; p < 4; ++p)
        #pragma unroll
        for (int r = 0; r < 3; ++r) {
            float fp = sh.pf[p][l][r];
            float n0v = fminf(fp, g0);
            float n1v = __builtin_amdgcn_fmed3f(fp, g0, g1);
            float n2v = fminf(g2, fmaxf(fp, g1));
            g0 = n0v; g1 = n1v; g2 = n2v;
        }
        int j0 = __float_as_int(g0) & 1023;
        int j1 = __float_as_int(g1) & 1023;
        int j2 = __float_as_int(g2) & 1023;
        // exact distances for the 3 winners
        const float4 p0 = pts4[(size_t)b * N2_ + j0];
        const float4 p1 = pts4[(size_t)b * N2_ + j1];
        const float4 p2 = pts4[(size_t)b * N2_ + j2];
        float d0 = ss + 2.0f * (p0.w - ((s0 * p0.x + s1 * p0.y) + s2 * p0.z));
        float d1 = ss + 2.0f * (p1.w - ((s0 * p1.x + s1 * p1.y) + s2 * p1.z));
        float d2 = ss + 2.0f * (p2.w - ((s0 * p2.x + s1 * p2.y) + s2 * p2.z));
        float r0 = 1.0f / (d0 + 1e-8f);
        float r1 = 1.0f / (d1 + 1e-8f);
        float r2 = 1.0f / (d2 + 1e-8f);
        float s  = (r0 + r1) + r2;
        rw[l][0] = r0 / s;  rw[l][1] = r1 / s;  rw[l][2] = r2 / s;
        ri[l][0] = j0;      ri[l][1] = j1;      ri[l][2] = j2;
    }
    __syncthreads();   // rw/ri ready; pf dead -> tile may alias

    // ---- Phase B: gather + blend + transpose ----
    for (int p = 0; p < 16; ++p) {
        int nl = p * 4 + w;
        float w0 = rw[nl][0], w1 = rw[nl][1], w2 = rw[nl][2];
        int i0g = ri[nl][0], i1g = ri[nl][1], i2g = ri[nl][2];
        const float4 va = ((const float4*)(x2 + ((size_t)b * N2_ + i0g) * C2_))[l];
        const float4 vb = ((const float4*)(x2 + ((size_t)b * N2_ + i1g) * C2_))[l];
        const float4 vc = ((const float4*)(x2 + ((size_t)b * N2_ + i2g) * C2_))[l];
        float fa[4] = {va.x, va.y, va.z, va.w};
        float fb[4] = {vb.x, vb.y, vb.z, vb.w};
        float fc[4] = {vc.x, vc.y, vc.z, vc.w};
        #pragma unroll
        for (int i = 0; i < 4; ++i) {
            float v = w0 * fa[i];
            v = fmaf(w1, fb[i], v);
            v = fmaf(w2, fc[i], v);
            sh.tile[l * 4 + i][nl] = f32_to_bf16_bits(v);
        }
    }
    __syncthreads();

    for (int r = 0; r < 64; ++r) {
        int c = r * 4 + w;
        interp_t[((size_t)b * C2_ + c) * K_ + n0 + l] = sh.tile[c][l];
    }
}

// ---------------------------------------------------------------------------
// Kernel 3: split-K GEMM. Zp[kc][b][o][c] partial over K-chunk kc.
// Tile 64(o) x 64(c), BK=32, 16 iters. Grid 2048 blocks -> 8/CU, 32 waves/CU.
// ---------------------------------------------------------------------------
#define LDA 40
__global__ __launch_bounds__(256) void gemm_kernel(
    const unsigned short* __restrict__ W1b,
    const unsigned short* __restrict__ interp_t,
    float* __restrict__ Zp)
{
    __shared__ unsigned short Alds[64][LDA];
    __shared__ unsigned short Blds[64][LDA];
    const int z  = blockIdx.z;
    const int b  = z >> 3;
    const int kc = z & 7;
    const int o0 = blockIdx.y * 64;
    const int c0 = blockIdx.x * 64;
    const int t = threadIdx.x;
    const int w = t >> 6, l = t & 63;
    const int row = t >> 2, q = t & 3;
    const int ob = (w >> 1) * 32, cb = (w & 1) * 32;
    const int m = l & 15, kq = l >> 4;

    const unsigned short* Wp = W1b + (size_t)(o0 + row) * K_ + kc * KCH_ + q * 8;
    const unsigned short* Bp = interp_t + ((size_t)b * C2_ + (c0 + row)) * K_ + kc * KCH_ + q * 8;

    float4v acc[2][2] = {};

    for (int kk = 0; kk < KCH_; kk += 32) {
        uint4 av = *(const uint4*)(Wp + kk);
        uint4 bv = *(const uint4*)(Bp + kk);
        *(uint4*)&Alds[row][q * 8] = av;
        *(uint4*)&Blds[row][q * 8] = bv;
        __syncthreads();
        short8 a0 = *(const short8*)&Alds[ob + m][kq * 8];
        short8 a1 = *(const short8*)&Alds[ob + 16 + m][kq * 8];
        short8 b0 = *(const short8*)&Blds[cb + m][kq * 8];
        short8 b1f = *(const short8*)&Blds[cb + 16 + m][kq * 8];
        acc[0][0] = __builtin_amdgcn_mfma_f32_16x16x32_bf16(a0, b0,  acc[0][0], 0, 0, 0);
        acc[0][1] = __builtin_amdgcn_mfma_f32_16x16x32_bf16(a0, b1f, acc[0][1], 0, 0, 0);
        acc[1][0] = __builtin_amdgcn_mfma_f32_16x16x32_bf16(a1, b0,  acc[1][0], 0, 0, 0);
        acc[1][1] = __builtin_amdgcn_mfma_f32_16x16x32_bf16(a1, b1f, acc[1][1], 0, 0, 0);
        __syncthreads();
    }

    float* Zslab = Zp + (size_t)kc * ZSLAB;
    #pragma unroll
    for (int mi = 0; mi < 2; ++mi)
    #pragma unroll
    for (int ni = 0; ni < 2; ++ni)
    #pragma unroll
    for (int r = 0; r < 4; ++r) {
        int o = o0 + ob + mi * 16 + kq * 4 + r;
        int c = c0 + cb + ni * 16 + m;
        Zslab[((size_t)b * OUT_ + o) * C2_ + c] = acc[mi][ni][r];
    }
}

// ---------------------------------------------------------------------------
// Kernel 4: reduce 8 partial slabs + bias -> final Z (slab 0), and
// accumulate BN stats (sum, sumsq per channel) via one atomic pair per block.
// ---------------------------------------------------------------------------
__global__ __launch_bounds__(256) void reduce_stats_kernel(
    float* __restrict__ Zp, const float* __restrict__ b1,
    float* __restrict__ accum)
{
    const int b  = blockIdx.x >> 4;
    const int oq = blockIdx.x & 15;
    const int c  = threadIdx.x;
    float s = 0.0f, s2 = 0.0f;
    for (int o16 = 0; o16 < 16; ++o16) {
        int o = oq * 16 + o16;
        size_t base = ((size_t)b * OUT_ + o) * C2_ + c;
        float v = b1[o];
        #pragma unroll
        for (int sl = 0; sl < SPLITK; ++sl)
            v += Zp[base + (size_t)sl * ZSLAB];
        Zp[base] = v;
        s += v; s2 += v * v;
    }
    atomicAdd(&accum[c], s);
    atomicAdd(&accum[C2_ + c], s2);
}

// ---------------------------------------------------------------------------
// Kernel 5: normalize + affine + ReLU + f32 store (reads final Z = slab 0).
// ---------------------------------------------------------------------------
__global__ __launch_bounds__(256) void bn_kernel(
    const float* __restrict__ Z, const float* __restrict__ accum,
    const float* __restrict__ gamma, const float* __restrict__ beta,
    float* __restrict__ out)
{
    const int i = (blockIdx.x * 256 + threadIdx.x) * 4;
    float4 z = *(const float4*)(Z + i);
    float vals[4] = {z.x, z.y, z.z, z.w};
    const int cb = i & 255;
    float res[4];
    #pragma unroll
    for (int j = 0; j < 4; ++j) {
        int c = cb + j;
        float mean = accum[c] * (1.0f / 4096.0f);
        float var  = accum[C2_ + c] * (1.0f / 4096.0f) - mean * mean;
        float rstd = 1.0f / sqrtf(var + 1e-5f);
        float v = gamma[c] * ((vals[j] - mean) * rstd) + beta[c];
        res[j] = fmaxf(v, 0.0f);
    }
    *(float4*)(out + i) = make_float4(res[0], res[1], res[2], res[3]);
}

// ---------------------------------------------------------------------------
extern "C" void kernel_launch(void* const* d_in, const int* in_sizes, int n_in,
                              void* d_out, int out_size, void* d_ws, size_t ws_size,
                              hipStream_t stream) {
    const float* x2    = (const float*)d_in[1];
    const float* xyz1  = (const float*)d_in[2];
    const float* xyz2  = (const float*)d_in[3];
    const float* W1    = (const float*)d_in[4];
    const float* b1    = (const float*)d_in[5];
    const float* gamma = (const float*)d_in[6];
    const float* beta  = (const float*)d_in[7];

    char* ws = (char*)d_ws;
    unsigned short* interp_t = (unsigned short*)(ws);              // 33,554,432 B
    unsigned short* W1b      = (unsigned short*)(ws + 33554432);   //  2,097,152 B
    float*          Zp       = (float*)(ws + 35651584);            // 33,554,432 B (8 slabs)
    float4*         pts4     = (float4*)(ws + 69206016);           //    262,144 B
    float*          accum    = (float*)(ws + 69468160);            //      2,048 B

    (void)hipMemsetAsync(accum, 0, 512 * sizeof(float), stream);

    w1cvt_kernel      <<<1024, 256, 0, stream>>>(W1, W1b);
    ptsprep_kernel    <<<64, 256, 0, stream>>>(xyz2, pts4);
    knn_interp_kernel <<<dim3(64, 16), 256, 0, stream>>>(xyz1, pts4, x2, interp_t);
    gemm_kernel       <<<dim3(4, 4, 128), 256, 0, stream>>>(W1b, interp_t, Zp);
    reduce_stats_kernel<<<256, 256, 0, stream>>>(Zp, b1, accum);
    bn_kernel         <<<1024, 256, 0, stream>>>(Zp, accum, gamma, beta,
                                                 (float*)d_out);
}

// Round 9
// 164.373 us; speedup vs baseline: 1.1231x; 1.1231x over previous
//
#include <hip/hip_runtime.h>
#include <hip/hip_bf16.h>
#include <float.h>

#define B_    16
#define N1_   4096
#define N2_   1024
#define C2_   256
#define OUT_  256
#define K_    4096    // GEMM K == N1
#define SPLITK 8
#define KCH_  (K_ / SPLITK)     // 512
#define ZSLAB 1048576           // floats per partial slab (16*256*256)

typedef short short8 __attribute__((ext_vector_type(8)));
typedef float float4v __attribute__((ext_vector_type(4)));

static __device__ __forceinline__ unsigned short f32_to_bf16_bits(float v) {
    __hip_bfloat16 h = __float2bfloat16(v);
    return *(unsigned short*)&h;
}

// ---------------------------------------------------------------------------
// Kernel 0: convert W1 f32 -> bf16 for the MFMA GEMM.
// ---------------------------------------------------------------------------
__global__ __launch_bounds__(256) void w1cvt_kernel(
    const float* __restrict__ W1, unsigned short* __restrict__ W1b)
{
    const int i = (blockIdx.x * 256 + threadIdx.x) * 4;
    float4 v = *(const float4*)(W1 + i);
    ushort4 o;
    o.x = f32_to_bf16_bits(v.x);
    o.y = f32_to_bf16_bits(v.y);
    o.z = f32_to_bf16_bits(v.z);
    o.w = f32_to_bf16_bits(v.w);
    *(ushort4*)(W1b + i) = o;
}

// ---------------------------------------------------------------------------
// Fused knn + interp. Candidates staged in LDS (broadcast ds_read_b128 —
// R8's scalar-load path thrashed the scalar cache; reverted). Key = distance
// dk = max(ss + 2*(0.5|p|^2 - dot), 0)  (non-negative -> float order == bit
// order) with the global candidate index packed into the low 10 mantissa
// bits; smaller index wins ties (JAX stable top-k). Truncation is 2^-13
// relative to d: flips only between near-equal-distance neighbors (weights
// match to ~1e-4 -> benign; validated absmax 0.035 in R8). Top-3 kept by a
// 4-op float network (min / med3 / min(max)); distance chain uses negated
// query so the subtract folds into fma (~10 VALU/candidate).
// Winners' distances recomputed exactly. Phase B: gather x2 rows, blend,
// LDS-transpose, write bf16 interp_t[b][c][n] (K-major).
// ---------------------------------------------------------------------------
#define TPAD 65
struct KnnSh {
    float4 pts[N2_];          // (x, y, z, 0.5*|p|^2)   16 KB
    float  pf[4][64][3];      // per-wave packed top-3   3 KB
};
union ShUnion {
    KnnSh a;
    unsigned short tile[C2_][TPAD];   // transpose tile  33.3 KB
};

__global__ __launch_bounds__(256) void knn_interp_kernel(
    const float* __restrict__ xyz1,
    const float* __restrict__ xyz2,
    const float* __restrict__ x2,
    unsigned short* __restrict__ interp_t)
{
    __shared__ ShUnion sh;
    __shared__ float rw[64][3];
    __shared__ int   ri[64][3];

    const int b  = blockIdx.y;
    const int n0 = blockIdx.x * 64;
    const int t  = threadIdx.x;
    const int w  = t >> 6;
    const int l  = t & 63;

    // ---- stage candidates into LDS ----
    for (int r = 0; r < 4; ++r) {
        int j = r * 256 + t;
        const float* p = xyz2 + ((size_t)b * N2_ + j) * 3;
        float x = p[0], y = p[1], z = p[2];
        sh.a.pts[j] = make_float4(x, y, z, 0.5f * ((x * x + y * y) + z * z));
    }
    __syncthreads();

    const int n1 = n0 + l;
    const float* q = xyz1 + ((size_t)b * N1_ + n1) * 3;
    const float s0 = q[0], s1 = q[1], s2 = q[2];
    const float ns0 = -s0, ns1 = -s1, ns2 = -s2;
    const float ss = (s0 * s0 + s1 * s1) + s2 * s2;

    // ---- Phase A: scan (wave w covers blocked quarter [256w, 256w+256)) ----
    const int jbase = w << 8;
    float f0 = FLT_MAX, f1 = FLT_MAX, f2 = FLT_MAX;

    #pragma unroll 4
    for (int jj = 0; jj < 256; ++jj) {
        const int j = jbase + jj;
        float4 pq = sh.a.pts[j];
        // acc = 0.5|p|^2 - dot(q,p), subtract folded into fma chain
        float acc = fmaf(ns0, pq.x, pq.w);
        acc = fmaf(ns1, pq.y, acc);
        acc = fmaf(ns2, pq.z, acc);
        float dk = fmaxf(fmaf(2.0f, acc, ss), 0.0f);
        float fp = __int_as_float((__float_as_int(dk) & 0xFFFFFC00) | j);
        float nf0 = fminf(fp, f0);
        float nf1 = __builtin_amdgcn_fmed3f(fp, f0, f1);
        float nf2 = fminf(f2, fmaxf(fp, f1));
        f0 = nf0; f1 = nf1; f2 = nf2;
    }

    sh.a.pf[w][l][0] = f0; sh.a.pf[w][l][1] = f1; sh.a.pf[w][l][2] = f2;
    __syncthreads();

    if (w == 0) {
        float g0 = FLT_MAX, g1 = FLT_MAX, g2 = FLT_MAX;
        #pragma unroll
        for (int p = 0; p < 4; ++p)
        #pragma unroll
        for (int r = 0; r < 3; ++r) {
            float fp = sh.a.pf[p][l][r];
            float n0v = fminf(fp, g0);
            float n1v = __builtin_amdgcn_fmed3f(fp, g0, g1);
            float n2v = fminf(g2, fmaxf(fp, g1));
            g0 = n0v; g1 = n1v; g2 = n2v;
        }
        int j0 = __float_as_int(g0) & 1023;
        int j1 = __float_as_int(g1) & 1023;
        int j2 = __float_as_int(g2) & 1023;
        // exact distances for the 3 winners (pts still live in LDS)
        const float4 p0 = sh.a.pts[j0];
        const float4 p1 = sh.a.pts[j1];
        const float4 p2 = sh.a.pts[j2];
        float d0 = ss + 2.0f * (p0.w - ((s0 * p0.x + s1 * p0.y) + s2 * p0.z));
        float d1 = ss + 2.0f * (p1.w - ((s0 * p1.x + s1 * p1.y) + s2 * p1.z));
        float d2 = ss + 2.0f * (p2.w - ((s0 * p2.x + s1 * p2.y) + s2 * p2.z));
        float r0 = 1.0f / (d0 + 1e-8f);
        float r1 = 1.0f / (d1 + 1e-8f);
        float r2 = 1.0f / (d2 + 1e-8f);
        float s  = (r0 + r1) + r2;
        rw[l][0] = r0 / s;  rw[l][1] = r1 / s;  rw[l][2] = r2 / s;
        ri[l][0] = j0;      ri[l][1] = j1;      ri[l][2] = j2;
    }
    __syncthreads();   // rw/ri ready; pts/pf dead -> tile may alias

    // ---- Phase B: gather + blend + transpose ----
    for (int p = 0; p < 16; ++p) {
        int nl = p * 4 + w;
        float w0 = rw[nl][0], w1 = rw[nl][1], w2 = rw[nl][2];
        int i0g = ri[nl][0], i1g = ri[nl][1], i2g = ri[nl][2];
        const float4 va = ((const float4*)(x2 + ((size_t)b * N2_ + i0g) * C2_))[l];
        const float4 vb = ((const float4*)(x2 + ((size_t)b * N2_ + i1g) * C2_))[l];
        const float4 vc = ((const float4*)(x2 + ((size_t)b * N2_ + i2g) * C2_))[l];
        float fa[4] = {va.x, va.y, va.z, va.w};
        float fb[4] = {vb.x, vb.y, vb.z, vb.w};
        float fc[4] = {vc.x, vc.y, vc.z, vc.w};
        #pragma unroll
        for (int i = 0; i < 4; ++i) {
            float v = w0 * fa[i];
            v = fmaf(w1, fb[i], v);
            v = fmaf(w2, fc[i], v);
            sh.tile[l * 4 + i][nl] = f32_to_bf16_bits(v);
        }
    }
    __syncthreads();

    for (int r = 0; r < 64; ++r) {
        int c = r * 4 + w;
        interp_t[((size_t)b * C2_ + c) * K_ + n0 + l] = sh.tile[c][l];
    }
}

// ---------------------------------------------------------------------------
// Kernel 3: split-K GEMM. Zp[kc][b][o][c] partial over K-chunk kc.
// Tile 64(o) x 64(c), BK=32, 16 iters. Grid 2048 blocks -> 8/CU, 32 waves/CU.
// ---------------------------------------------------------------------------
#define LDA 40
__global__ __launch_bounds__(256) void gemm_kernel(
    const unsigned short* __restrict__ W1b,
    const unsigned short* __restrict__ interp_t,
    float* __restrict__ Zp)
{
    __shared__ unsigned short Alds[64][LDA];
    __shared__ unsigned short Blds[64][LDA];
    const int z  = blockIdx.z;
    const int b  = z >> 3;
    const int kc = z & 7;
    const int o0 = blockIdx.y * 64;
    const int c0 = blockIdx.x * 64;
    const int t = threadIdx.x;
    const int w = t >> 6, l = t & 63;
    const int row = t >> 2, q = t & 3;
    const int ob = (w >> 1) * 32, cb = (w & 1) * 32;
    const int m = l & 15, kq = l >> 4;

    const unsigned short* Wp = W1b + (size_t)(o0 + row) * K_ + kc * KCH_ + q * 8;
    const unsigned short* Bp = interp_t + ((size_t)b * C2_ + (c0 + row)) * K_ + kc * KCH_ + q * 8;

    float4v acc[2][2] = {};

    for (int kk = 0; kk < KCH_; kk += 32) {
        uint4 av = *(const uint4*)(Wp + kk);
        uint4 bv = *(const uint4*)(Bp + kk);
        *(uint4*)&Alds[row][q * 8] = av;
        *(uint4*)&Blds[row][q * 8] = bv;
        __syncthreads();
        short8 a0 = *(const short8*)&Alds[ob + m][kq * 8];
        short8 a1 = *(const short8*)&Alds[ob + 16 + m][kq * 8];
        short8 b0 = *(const short8*)&Blds[cb + m][kq * 8];
        short8 b1f = *(const short8*)&Blds[cb + 16 + m][kq * 8];
        acc[0][0] = __builtin_amdgcn_mfma_f32_16x16x32_bf16(a0, b0,  acc[0][0], 0, 0, 0);
        acc[0][1] = __builtin_amdgcn_mfma_f32_16x16x32_bf16(a0, b1f, acc[0][1], 0, 0, 0);
        acc[1][0] = __builtin_amdgcn_mfma_f32_16x16x32_bf16(a1, b0,  acc[1][0], 0, 0, 0);
        acc[1][1] = __builtin_amdgcn_mfma_f32_16x16x32_bf16(a1, b1f, acc[1][1], 0, 0, 0);
        __syncthreads();
    }

    float* Zslab = Zp + (size_t)kc * ZSLAB;
    #pragma unroll
    for (int mi = 0; mi < 2; ++mi)
    #pragma unroll
    for (int ni = 0; ni < 2; ++ni)
    #pragma unroll
    for (int r = 0; r < 4; ++r) {
        int o = o0 + ob + mi * 16 + kq * 4 + r;
        int c = c0 + cb + ni * 16 + m;
        Zslab[((size_t)b * OUT_ + o) * C2_ + c] = acc[mi][ni][r];
    }
}

// ---------------------------------------------------------------------------
// Kernel 4: reduce 8 partial slabs + bias -> final Z (slab 0), and
// accumulate BN stats (sum, sumsq per channel) via one atomic pair per block.
// ---------------------------------------------------------------------------
__global__ __launch_bounds__(256) void reduce_stats_kernel(
    float* __restrict__ Zp, const float* __restrict__ b1,
    float* __restrict__ accum)
{
    const int b  = blockIdx.x >> 4;
    const int oq = blockIdx.x & 15;
    const int c  = threadIdx.x;
    float s = 0.0f, s2 = 0.0f;
    for (int o16 = 0; o16 < 16; ++o16) {
        int o = oq * 16 + o16;
        size_t base = ((size_t)b * OUT_ + o) * C2_ + c;
        float v = b1[o];
        #pragma unroll
        for (int sl = 0; sl < SPLITK; ++sl)
            v += Zp[base + (size_t)sl * ZSLAB];
        Zp[base] = v;
        s += v; s2 += v * v;
    }
    atomicAdd(&accum[c], s);
    atomicAdd(&accum[C2_ + c], s2);
}

// ---------------------------------------------------------------------------
// Kernel 5: normalize + affine + ReLU + f32 store (reads final Z = slab 0).
// ---------------------------------------------------------------------------
__global__ __launch_bounds__(256) void bn_kernel(
    const float* __restrict__ Z, const float* __restrict__ accum,
    const float* __restrict__ gamma, const float* __restrict__ beta,
    float* __restrict__ out)
{
    const int i = (blockIdx.x * 256 + threadIdx.x) * 4;
    float4 z = *(const float4*)(Z + i);
    float vals[4] = {z.x, z.y, z.z, z.w};
    const int cb = i & 255;
    float res[4];
    #pragma unroll
    for (int j = 0; j < 4; ++j) {
        int c = cb + j;
        float mean = accum[c] * (1.0f / 4096.0f);
        float var  = accum[C2_ + c] * (1.0f / 4096.0f) - mean * mean;
        float rstd = 1.0f / sqrtf(var + 1e-5f);
        float v = gamma[c] * ((vals[j] - mean) * rstd) + beta[c];
        res[j] = fmaxf(v, 0.0f);
    }
    *(float4*)(out + i) = make_float4(res[0], res[1], res[2], res[3]);
}

// ---------------------------------------------------------------------------
extern "C" void kernel_launch(void* const* d_in, const int* in_sizes, int n_in,
                              void* d_out, int out_size, void* d_ws, size_t ws_size,
                              hipStream_t stream) {
    const float* x2    = (const float*)d_in[1];
    const float* xyz1  = (const float*)d_in[2];
    const float* xyz2  = (const float*)d_in[3];
    const float* W1    = (const float*)d_in[4];
    const float* b1    = (const float*)d_in[5];
    const float* gamma = (const float*)d_in[6];
    const float* beta  = (const float*)d_in[7];

    char* ws = (char*)d_ws;
    unsigned short* interp_t = (unsigned short*)(ws);              // 33,554,432 B
    unsigned short* W1b      = (unsigned short*)(ws + 33554432);   //  2,097,152 B
    float*          Zp       = (float*)(ws + 35651584);            // 33,554,432 B (8 slabs)
    float*          accum    = (float*)(ws + 69206016);            //      2,048 B

    (void)hipMemsetAsync(accum, 0, 512 * sizeof(float), stream);

    w1cvt_kernel      <<<1024, 256, 0, stream>>>(W1, W1b);
    knn_interp_kernel <<<dim3(64, 16), 256, 0, stream>>>(xyz1, xyz2, x2, interp_t);
    gemm_kernel       <<<dim3(4, 4, 128), 256, 0, stream>>>(W1b, interp_t, Zp);
    reduce_stats_kernel<<<256, 256, 0, stream>>>(Zp, b1, accum);
    bn_kernel         <<<1024, 256, 0, stream>>>(Zp, accum, gamma, beta,
                                                 (float*)d_out);
}